// Round 3
// baseline (181.250 us; speedup 1.0000x reference)
//
#include <hip/hip_runtime.h>
#include <hip/hip_cooperative_groups.h>

namespace cg = cooperative_groups;

#define B_ 16
#define M_ 200
#define S_ 32
#define C_ 2048
#define V_ 32000
#define D_ 128
#define HOPS_ 3
#define NBLK 256
#define NTHR 1024
#define NTOT (NBLK * NTHR)   // 262144 threads

// One cooperative kernel, 4 phases separated by grid.sync():
//  P1: embedding bags  m[b,i,:]=sum_s embA[stories], u[b,:]=sum_s embA[query]
//  P2: 3 memory hops (blocks 0..15, one per batch)
//  P3: P[v,b] = u[b,:] . embW[v,:]
//  P4: logits[b,c] = sum_s P[cand[c,s],b] + sum_s P[E[b,c,s],b]
__global__ void __launch_bounds__(NTHR) k_fused(
        const int* __restrict__ stories, const int* __restrict__ query,
        const int* __restrict__ E, const int* __restrict__ cand,
        const float* __restrict__ embA, const float* __restrict__ embW,
        const float* __restrict__ Hw, const float* __restrict__ Hb,
        float* __restrict__ out, float* __restrict__ m,
        float* __restrict__ u, float* __restrict__ P) {
    cg::grid_group grid = cg::this_grid();
    const int t = threadIdx.x;
    const int blk = blockIdx.x;
    const int gtid = blk * NTHR + t;

    __shared__ float su[D_];
    __shared__ float sattn[M_];
    __shared__ float sred[16 * D_];
    __shared__ float smx, ssum;

    // ---------------- Phase 1: embedding bags (32 lanes per bag) ----------------
    {
        int lane32 = t & 31;
        int sent = gtid >> 5;                       // 8192 slots >= 3216+16
        if (sent < B_ * M_ + B_) {
            const int* idx; float* dst;
            if (sent < B_ * M_) { idx = stories + sent * S_; dst = m + sent * D_; }
            else { int b = sent - B_ * M_; idx = query + b * S_; dst = u + b * D_; }
            float4 acc = {0.f, 0.f, 0.f, 0.f};
#pragma unroll 8
            for (int s = 0; s < S_; ++s) {
                const float4* row = (const float4*)(embA + (size_t)idx[s] * D_);
                float4 a = row[lane32];
                acc.x += a.x; acc.y += a.y; acc.z += a.z; acc.w += a.w;
            }
            ((float4*)dst)[lane32] = acc;
        }
    }
    grid.sync();

    // ---------------- Phase 2: hops (blocks 0..15, one batch each) ----------------
    if (blk < B_) {
        const int b = blk;
        const int lane = t & 63;
        const int wave = t >> 6;                    // 16 waves
        const float* mb = m + (size_t)b * M_ * D_;
        if (t < D_) su[t] = u[b * D_ + t];
        __syncthreads();
        for (int hop = 0; hop < HOPS_; ++hop) {
            // scores: attn[i] = m[b,i,:] . u  (one row per wave, shfl reduce)
            float2 uu = ((const float2*)su)[lane];
            for (int i = wave; i < M_; i += 16) {
                float2 mv = ((const float2*)(mb + i * D_))[lane];
                float p = mv.x * uu.x + mv.y * uu.y;
#pragma unroll
                for (int o = 32; o; o >>= 1) p += __shfl_xor(p, o);
                if (lane == 0) sattn[i] = p;
            }
            __syncthreads();
            // softmax max/sum by wave 0
            if (wave == 0) {
                float mx = -3.0e38f;
                for (int i = lane; i < M_; i += 64) mx = fmaxf(mx, sattn[i]);
#pragma unroll
                for (int o = 32; o; o >>= 1) mx = fmaxf(mx, __shfl_xor(mx, o));
                float sm = 0.f;
                for (int i = lane; i < M_; i += 64) sm += expf(sattn[i] - mx);
#pragma unroll
                for (int o = 32; o; o >>= 1) sm += __shfl_xor(sm, o);
                if (lane == 0) { smx = mx; ssum = sm; }
            }
            __syncthreads();
            if (t < M_) sattn[t] = expf(sattn[t] - smx) * (1.f / ssum);
            __syncthreads();
            // o[d] = sum_i attn[i]*m[b,i,d]  (per-wave partials)
            float2 oacc = {0.f, 0.f};
            for (int i = wave; i < M_; i += 16) {
                float a = sattn[i];
                float2 mv = ((const float2*)(mb + i * D_))[lane];
                oacc.x += a * mv.x; oacc.y += a * mv.y;
            }
            ((float2*)sred)[wave * 64 + lane] = oacc;
            __syncthreads();
            // u_new[d] = Hb[d] + o[d] + sum_k Hw[d,k]*su[k]   (8 lanes per d)
            int d  = t >> 3;
            int k8 = t & 7;
            float tot = sred[k8 * D_ + d] + sred[(k8 + 8) * D_ + d];
            for (int k = k8; k < D_; k += 8) tot += Hw[d * D_ + k] * su[k];
#pragma unroll
            for (int o = 1; o < 8; o <<= 1) tot += __shfl_xor(tot, o);
            float un = Hb[d] + tot;
            __syncthreads();
            if (k8 == 0) su[d] = un;
            __syncthreads();
        }
        if (t < D_) u[b * D_ + t] = su[t];
    }
    grid.sync();

    // ---------------- Phase 3: P[v,b] = u[b,:] . embW[v,:] ----------------
    for (int g = gtid; g < B_ * V_; g += NTOT) {     // g = v*16 + b
        int b = g & (B_ - 1);
        int v = g >> 4;
        const float4* w  = (const float4*)(embW + (size_t)v * D_);
        const float4* uu = (const float4*)(u + b * D_);
        float acc = 0.f;
#pragma unroll 8
        for (int j = 0; j < D_ / 4; ++j) {
            float4 a = w[j]; float4 x = uu[j];
            acc += a.x * x.x + a.y * x.y + a.z * x.z + a.w * x.w;
        }
        P[v * B_ + b] = acc;
    }
    grid.sync();

    // ---------------- Phase 4: logits (4 lanes per (b,c), shfl combine) ----------------
    {
        int g4 = gtid;                               // (b*C + c)*4 + q
        if (g4 < B_ * C_ * 4) {
            int q = g4 & 3;
            int g = g4 >> 2;
            int c = g & (C_ - 1);
            int b = g >> 11;
            const int4* cs = (const int4*)(cand + c * S_ + q * 8);
            const int4* es = (const int4*)(E + (size_t)g * S_ + q * 8);
            float acc = 0.f;
#pragma unroll
            for (int j = 0; j < 2; ++j) {
                int4 wv = cs[j];
                acc += P[wv.x * B_ + b] + P[wv.y * B_ + b] + P[wv.z * B_ + b] + P[wv.w * B_ + b];
                int4 ev = es[j];
                acc += P[ev.x * B_ + b] + P[ev.y * B_ + b] + P[ev.z * B_ + b] + P[ev.w * B_ + b];
            }
            acc += __shfl_xor(acc, 1);
            acc += __shfl_xor(acc, 2);
            if (q == 0) out[g] = acc;
        }
    }
}

extern "C" void kernel_launch(void* const* d_in, const int* in_sizes, int n_in,
                              void* d_out, int out_size, void* d_ws, size_t ws_size,
                              hipStream_t stream) {
    const int*   stories = (const int*)d_in[0];
    const int*   query   = (const int*)d_in[1];
    const int*   E       = (const int*)d_in[2];
    const int*   cand    = (const int*)d_in[3];
    const float* embA    = (const float*)d_in[4];
    const float* embW    = (const float*)d_in[5];
    const float* Hw      = (const float*)d_in[6];
    const float* Hb      = (const float*)d_in[7];
    float* out = (float*)d_out;

    char* ws = (char*)d_ws;
    float* u = (float*)ws;                                      // B*D       =   8 KB
    float* m = (float*)(ws + 8192);                             // B*M*D f32 = 1.6 MB
    float* P = (float*)(ws + 8192 + (size_t)B_ * M_ * D_ * 4);  // V*B  f32  = 2.0 MB

    void* args[] = { (void*)&stories, (void*)&query, (void*)&E, (void*)&cand,
                     (void*)&embA, (void*)&embW, (void*)&Hw, (void*)&Hb,
                     (void*)&out, (void*)&m, (void*)&u, (void*)&P };
    hipLaunchCooperativeKernel((const void*)k_fused, dim3(NBLK), dim3(NTHR),
                               args, 0, stream);
}

// Round 5
// 143.505 us; speedup vs baseline: 1.2630x; 1.2630x over previous
//
#include <hip/hip_runtime.h>

#define B_ 16
#define M_ 200
#define S_ 32
#define C_ 2048
#define V_ 32000
#define D_ 128
#define HOPS_ 3
#define NBLK 256
#define NTHR 1024

// Lightweight device-scope grid barrier. Counters zeroed by hipMemsetAsync
// each launch. Every block calls each barrier exactly once per launch.
__device__ __forceinline__ void gbar(unsigned* ctr) {
    __syncthreads();
    if (threadIdx.x == 0) {
        __builtin_amdgcn_fence(__ATOMIC_RELEASE, "agent");
        __hip_atomic_fetch_add(ctr, 1u, __ATOMIC_RELAXED, __HIP_MEMORY_SCOPE_AGENT);
        while (__hip_atomic_load(ctr, __ATOMIC_RELAXED, __HIP_MEMORY_SCOPE_AGENT) < (unsigned)NBLK)
            __builtin_amdgcn_s_sleep(8);
        __builtin_amdgcn_fence(__ATOMIC_ACQUIRE, "agent");
    }
    __syncthreads();
}

// One cooperative kernel, 4 phases, 3 custom barriers.
//  P1: embedding bags -> m[b,i,:], u0[b,:]
//  P2: 3 memory hops (blocks 0..15)
//  P3: Pt[b][v] = u[b,:] . embW[v,:]  (b-major via LDS transpose)
//  P4: logits[b,c] = sum_s Pt[b][cand[c,s]] + sum_s Pt[b][E[b,c,s]]
__global__ void __launch_bounds__(NTHR) k_fused(
        const int* __restrict__ stories, const int* __restrict__ query,
        const int* __restrict__ E, const int* __restrict__ cand,
        const float* __restrict__ embA, const float* __restrict__ embW,
        const float* __restrict__ Hw, const float* __restrict__ Hb,
        float* __restrict__ out, float* __restrict__ m,
        float* __restrict__ u, float* __restrict__ Pt, unsigned* __restrict__ bc) {
    const int t = threadIdx.x;
    const int blk = blockIdx.x;
    const int gtid = blk * NTHR + t;

    __shared__ float su[D_];
    __shared__ float sattn[M_];
    __shared__ float sred[16 * D_];   // phase 2 partials; reused as transpose tile in P3
    __shared__ float smx, ssum;

    // ---------------- Phase 1: embedding bags (32 lanes per bag) ----------------
    {
        int lane32 = t & 31;
        int sent = gtid >> 5;
        if (sent < B_ * M_ + B_) {
            const int* idx; float* dst;
            if (sent < B_ * M_) { idx = stories + sent * S_; dst = m + sent * D_; }
            else { int b = sent - B_ * M_; idx = query + b * S_; dst = u + b * D_; }
            float4 acc = {0.f, 0.f, 0.f, 0.f};
#pragma unroll 8
            for (int s = 0; s < S_; ++s) {
                const float4* row = (const float4*)(embA + (size_t)idx[s] * D_);
                float4 a = row[lane32];
                acc.x += a.x; acc.y += a.y; acc.z += a.z; acc.w += a.w;
            }
            ((float4*)dst)[lane32] = acc;
        }
    }
    gbar(bc + 0);

    // ---------------- Phase 2: hops (blocks 0..15, one batch each) ----------------
    if (blk < B_) {
        const int b = blk;
        const int lane = t & 63;
        const int wave = t >> 6;
        const float* mb = m + (size_t)b * M_ * D_;
        if (t < D_) su[t] = u[b * D_ + t];
        __syncthreads();
        for (int hop = 0; hop < HOPS_; ++hop) {
            float2 uu = ((const float2*)su)[lane];
            for (int i = wave; i < M_; i += 16) {
                float2 mv = ((const float2*)(mb + i * D_))[lane];
                float p = mv.x * uu.x + mv.y * uu.y;
#pragma unroll
                for (int o = 32; o; o >>= 1) p += __shfl_xor(p, o);
                if (lane == 0) sattn[i] = p;
            }
            __syncthreads();
            if (wave == 0) {
                float mx = -3.0e38f;
                for (int i = lane; i < M_; i += 64) mx = fmaxf(mx, sattn[i]);
#pragma unroll
                for (int o = 32; o; o >>= 1) mx = fmaxf(mx, __shfl_xor(mx, o));
                float sm = 0.f;
                for (int i = lane; i < M_; i += 64) sm += expf(sattn[i] - mx);
#pragma unroll
                for (int o = 32; o; o >>= 1) sm += __shfl_xor(sm, o);
                if (lane == 0) { smx = mx; ssum = sm; }
            }
            __syncthreads();
            if (t < M_) sattn[t] = expf(sattn[t] - smx) * (1.f / ssum);
            __syncthreads();
            float2 oacc = {0.f, 0.f};
            for (int i = wave; i < M_; i += 16) {
                float a = sattn[i];
                float2 mv = ((const float2*)(mb + i * D_))[lane];
                oacc.x += a * mv.x; oacc.y += a * mv.y;
            }
            ((float2*)sred)[wave * 64 + lane] = oacc;
            __syncthreads();
            int d  = t >> 3;
            int k8 = t & 7;
            float tot = sred[k8 * D_ + d] + sred[(k8 + 8) * D_ + d];
            for (int k = k8; k < D_; k += 8) tot += Hw[d * D_ + k] * su[k];
#pragma unroll
            for (int o = 1; o < 8; o <<= 1) tot += __shfl_xor(tot, o);
            float un = Hb[d] + tot;
            __syncthreads();
            if (k8 == 0) su[d] = un;
            __syncthreads();
        }
        if (t < D_) u[b * D_ + t] = su[t];
    }
    gbar(bc + 16);

    // ---------------- Phase 3: Pt[b][v] = u[b,:] . embW[v,:] ----------------
    // block-iter bi covers v-range [bi*64, bi*64+64); 500 block-iters total.
    {
        float* strans = sred;   // 64x17 tile (1088 floats <= 2048)
#pragma unroll
        for (int it = 0; it < 2; ++it) {
            int bi = blk + it * NBLK;
            if (bi < V_ / 64) {
                int v = bi * 64 + (t >> 4);
                int b = t & 15;
                const float4* w  = (const float4*)(embW + (size_t)v * D_);
                const float4* uu = (const float4*)(u + b * D_);
                float acc = 0.f;
#pragma unroll 8
                for (int j = 0; j < D_ / 4; ++j) {
                    float4 a = w[j]; float4 x = uu[j];
                    acc += a.x * x.x + a.y * x.y + a.z * x.z + a.w * x.w;
                }
                strans[(t >> 4) * 17 + b] = acc;
            }
            __syncthreads();
            if (bi < V_ / 64) {
                int b_o = t >> 6;       // 0..15
                int v_o = t & 63;       // 0..63
                Pt[(size_t)b_o * V_ + bi * 64 + v_o] = strans[v_o * 17 + b_o];
            }
            __syncthreads();
        }
    }
    gbar(bc + 32);

    // ---------------- Phase 4: logits, b-pinned blocks for Pt locality ----------------
    {
        int b    = blk >> 4;            // 0..15
        int tile = blk & 15;            // 0..15 -> 128 c each
        int c    = tile * 128 + (t >> 3);
        int q    = t & 7;
        const float* Pb = Pt + (size_t)b * V_;
        const int4* src;
        if (q < 4) src = (const int4*)(cand + c * S_ + q * 8);
        else       src = (const int4*)(E + ((size_t)(b * C_ + c)) * S_ + (q - 4) * 8);
        float acc = 0.f;
#pragma unroll
        for (int j = 0; j < 2; ++j) {
            int4 w = src[j];
            acc += Pb[w.x] + Pb[w.y] + Pb[w.z] + Pb[w.w];
        }
        acc += __shfl_xor(acc, 1);
        acc += __shfl_xor(acc, 2);
        acc += __shfl_xor(acc, 4);
        if (q == 0) out[b * C_ + c] = acc;
    }
}

extern "C" void kernel_launch(void* const* d_in, const int* in_sizes, int n_in,
                              void* d_out, int out_size, void* d_ws, size_t ws_size,
                              hipStream_t stream) {
    const int*   stories = (const int*)d_in[0];
    const int*   query   = (const int*)d_in[1];
    const int*   E       = (const int*)d_in[2];
    const int*   cand    = (const int*)d_in[3];
    const float* embA    = (const float*)d_in[4];
    const float* embW    = (const float*)d_in[5];
    const float* Hw      = (const float*)d_in[6];
    const float* Hb      = (const float*)d_in[7];
    float* out = (float*)d_out;

    char* ws = (char*)d_ws;
    unsigned* bc = (unsigned*)ws;                                   // 3 ctrs @ uint off 0,16,32
    float* u  = (float*)(ws + 1024);                                // 8 KB
    float* m  = (float*)(ws + 1024 + 8192);                         // 1.6 MB
    float* Pt = (float*)(ws + 1024 + 8192 + (size_t)B_ * M_ * D_ * 4); // 2.0 MB

    (void)hipMemsetAsync(ws, 0, 256, stream);   // zero barrier counters each launch

    void* args[] = { (void*)&stories, (void*)&query, (void*)&E, (void*)&cand,
                     (void*)&embA, (void*)&embW, (void*)&Hw, (void*)&Hb,
                     (void*)&out, (void*)&m, (void*)&u, (void*)&Pt, (void*)&bc };
    (void)hipLaunchCooperativeKernel((const void*)k_fused, dim3(NBLK), dim3(NTHR),
                                     args, 0, stream);
}